// Round 7
// baseline (223.887 us; speedup 1.0000x reference)
//
#include <hip/hip_runtime.h>

// TFAdaptiveAvgPool1D: in [32,1024,4096] f32 -> out [32,1024,512] f32.
// 4096/512 = 8 => out[w] = mean(in[8w:8w+8]).
//
// R5 structure (one output float4 / 128B read per thread, no loop, exact
// grid, max occupancy) + nontemporal hints via clang ext_vector_type
// (__builtin_nontemporal_* rejects HIP_vector_type structs).
// Input is 512MiB read-once (> 256MiB L3, zero reuse), output 64MiB
// write-once -> `nt` loads/stores skip cache allocation.

typedef float f32x4 __attribute__((ext_vector_type(4)));

__global__ void __launch_bounds__(256)
TFAdaptiveAvgPool1D_40003325395108_kernel(const f32x4* __restrict__ in4,
                                          f32x4* __restrict__ out4) {
    const long long i = (long long)blockIdx.x * 256 + threadIdx.x;
    const f32x4* p = in4 + i * 8;
    f32x4 a0 = __builtin_nontemporal_load(p + 0);
    f32x4 a1 = __builtin_nontemporal_load(p + 1);
    f32x4 a2 = __builtin_nontemporal_load(p + 2);
    f32x4 a3 = __builtin_nontemporal_load(p + 3);
    f32x4 a4 = __builtin_nontemporal_load(p + 4);
    f32x4 a5 = __builtin_nontemporal_load(p + 5);
    f32x4 a6 = __builtin_nontemporal_load(p + 6);
    f32x4 a7 = __builtin_nontemporal_load(p + 7);
    f32x4 r;
    r.x = ((a0.x + a0.y) + (a0.z + a0.w) + (a1.x + a1.y) + (a1.z + a1.w)) * 0.125f;
    r.y = ((a2.x + a2.y) + (a2.z + a2.w) + (a3.x + a3.y) + (a3.z + a3.w)) * 0.125f;
    r.z = ((a4.x + a4.y) + (a4.z + a4.w) + (a5.x + a5.y) + (a5.z + a5.w)) * 0.125f;
    r.w = ((a6.x + a6.y) + (a6.z + a6.w) + (a7.x + a7.y) + (a7.z + a7.w)) * 0.125f;
    __builtin_nontemporal_store(r, out4 + i);
}

extern "C" void kernel_launch(void* const* d_in, const int* in_sizes, int n_in,
                              void* d_out, int out_size, void* d_ws, size_t ws_size,
                              hipStream_t stream) {
    const f32x4* in4 = (const f32x4*)d_in[0];   // [32,1024,4096] f32
    f32x4* out4 = (f32x4*)d_out;                // [32,1024,512] f32 as float4

    const int n4 = out_size / 4;                // 4,194,304
    const int block = 256;
    const int grid = n4 / block;                // 16384, exact
    TFAdaptiveAvgPool1D_40003325395108_kernel<<<grid, block, 0, stream>>>(in4, out4);
}

// Round 8
// 119.130 us; speedup vs baseline: 1.8794x; 1.8794x over previous
//
#include <hip/hip_runtime.h>

// TFAdaptiveAvgPool1D: in [32,1024,4096] f32 -> out [32,1024,512] f32.
// 4096/512 = 8 => out[w] = mean(in[8w:8w+8]).
//
// Copy-pattern loads + per-wave LDS reorg:
//  - Each wave owns one contiguous 8KB input chunk (2048 floats = 256 windows).
//  - 8 fully-coalesced dwordx4 loads (16B/lane; each 128B line requested ONCE,
//    vs 8x in the 128B-per-lane layout -- the nt experiment showed L2 was
//    absorbing that 8x redundancy, at a cost).
//  - Half-window sums paired via __shfl_xor(.,1) (DPP, cheap), even lanes
//    write 256 window means to a private 1KB LDS slab (32 lanes -> 32 banks,
//    conflict-free), then one ds_read_b128 + one coalesced float4 store
//    (1KB/wave store).
// No loop, no tail: 65536 waves = 16384 blocks x 256 threads, exact.

typedef float f32x4 __attribute__((ext_vector_type(4)));

__global__ void __launch_bounds__(256)
TFAdaptiveAvgPool1D_40003325395108_kernel(const f32x4* __restrict__ in4,
                                          f32x4* __restrict__ out4) {
    __shared__ float lds[4][256];
    const int wid  = threadIdx.x >> 6;
    const int lane = threadIdx.x & 63;
    const long long wave = (long long)blockIdx.x * 4 + wid;

    const f32x4* p = in4 + wave * 512 + lane;   // 512 f32x4 per 8KB chunk
    float s[8];
#pragma unroll
    for (int k = 0; k < 8; ++k) {
        f32x4 a = p[k * 64];                    // coalesced: lane stride 16B
        s[k] = (a.x + a.y) + (a.z + a.w);       // half-window sum
    }
#pragma unroll
    for (int k = 0; k < 8; ++k)
        s[k] += __shfl_xor(s[k], 1);            // full window sum (lane pair)

    if ((lane & 1) == 0) {
        const int j = lane >> 1;                // 32 active lanes -> 32 banks
#pragma unroll
        for (int k = 0; k < 8; ++k)
            lds[wid][k * 32 + j] = s[k] * 0.125f;  // lds[W] = mean of window W
    }
    __syncthreads();

    const f32x4 r = *reinterpret_cast<const f32x4*>(&lds[wid][lane * 4]);
    out4[wave * 64 + lane] = r;                 // coalesced: 1KB per wave
}

extern "C" void kernel_launch(void* const* d_in, const int* in_sizes, int n_in,
                              void* d_out, int out_size, void* d_ws, size_t ws_size,
                              hipStream_t stream) {
    const f32x4* in4 = (const f32x4*)d_in[0];   // [32,1024,4096] f32
    f32x4* out4 = (f32x4*)d_out;                // [32,1024,512] f32 as float4

    const int n4 = out_size / 4;                // 4,194,304 output float4
    const int block = 256;
    const int grid = n4 / (block / 4 * 16);     // one f32x4 out per lane... 
    // each wave produces 64 f32x4 -> block (4 waves) produces 256 f32x4
    // grid = n4 / 256 = 16384, exact:
    TFAdaptiveAvgPool1D_40003325395108_kernel<<<n4 / 256, block, 0, stream>>>(in4, out4);
    (void)grid;
}

// Round 9
// 113.357 us; speedup vs baseline: 1.9751x; 1.0509x over previous
//
#include <hip/hip_runtime.h>

// TFAdaptiveAvgPool1D: in [32,1024,4096] f32 -> out [32,1024,512] f32.
// 4096/512 = 8 => out[w] = mean(in[8w:8w+8]).
//
// FINAL (R5 config, best measured: 113.6 us = 5.32 TB/s aggregate).
// One output float4 (4 windows, 128B contiguous read) per thread, no loop,
// no tail (4,194,304 / 4 / 256 = 16384 blocks exact), ~40 VGPR -> full
// 32 waves/CU occupancy.
//
// Probed and rejected:
//  - R2/R8 wave-coalesced 16B/lane loads (+shuffle/LDS reorg): 144.6 / 119.1 us
//    -> request-per-line redundancy is absorbed by L1 at zero cost.
//  - R4 2-deep register pipeline (16 loads in flight): 120.0 us (neutral).
//  - R7 nontemporal loads/stores: 223.9 us (L1/L2 allocation is load-bearing).
//  - R3 32B/lane: 134.2 us.
// Read-dominated (8:1) streams plateau at ~5.3 TB/s vs 6.29 copy / 6.85 fill.

__global__ void __launch_bounds__(256)
TFAdaptiveAvgPool1D_40003325395108_kernel(const float4* __restrict__ in4,
                                          float4* __restrict__ out4) {
    const long long i = (long long)blockIdx.x * 256 + threadIdx.x;
    const float4* p = in4 + i * 8;
    float4 a0 = p[0], a1 = p[1], a2 = p[2], a3 = p[3];
    float4 a4 = p[4], a5 = p[5], a6 = p[6], a7 = p[7];
    float4 r;
    r.x = ((a0.x + a0.y) + (a0.z + a0.w) + (a1.x + a1.y) + (a1.z + a1.w)) * 0.125f;
    r.y = ((a2.x + a2.y) + (a2.z + a2.w) + (a3.x + a3.y) + (a3.z + a3.w)) * 0.125f;
    r.z = ((a4.x + a4.y) + (a4.z + a4.w) + (a5.x + a5.y) + (a5.z + a5.w)) * 0.125f;
    r.w = ((a6.x + a6.y) + (a6.z + a6.w) + (a7.x + a7.y) + (a7.z + a7.w)) * 0.125f;
    out4[i] = r;
}

extern "C" void kernel_launch(void* const* d_in, const int* in_sizes, int n_in,
                              void* d_out, int out_size, void* d_ws, size_t ws_size,
                              hipStream_t stream) {
    const float4* in4 = (const float4*)d_in[0];   // [32,1024,4096] f32
    float4* out4 = (float4*)d_out;                // [32,1024,512] f32 as float4

    const int n4 = out_size / 4;                  // 4,194,304
    const int block = 256;
    const int grid = n4 / block;                  // 16384, exact
    TFAdaptiveAvgPool1D_40003325395108_kernel<<<grid, block, 0, stream>>>(in4, out4);
}